// Round 1
// baseline (133.801 us; speedup 1.0000x reference)
//
#include <hip/hip_runtime.h>
#include <hip/hip_bf16.h>

using bf16x8 = __attribute__((ext_vector_type(8))) __bf16;
using f32x4  = __attribute__((ext_vector_type(4))) float;

#define MTOT   16384
#define DMODEL 1024
#define DSTATE 64
#define KBIG   1088
#define NCH    8
#define TC     512

__device__ __forceinline__ ushort f2b(float f) {
  __hip_bfloat16 h = __float2bfloat16(f);
  return *reinterpret_cast<ushort*>(&h);
}

// Build Wt[n][k] = bf16( k<64 ? C[k][n] : D[k-64][n] ), Btu[s][k] = bf16(B[k][s]),
// aSig[s] = sigmoid(A_diag[s])
__global__ void prep_params(const float* __restrict__ A_diag, const float* __restrict__ B,
                            const float* __restrict__ C, const float* __restrict__ D,
                            ushort* __restrict__ Wt, ushort* __restrict__ Btu,
                            float* __restrict__ aSig) {
  int i = blockIdx.x * blockDim.x + threadIdx.x;
  int stride = gridDim.x * blockDim.x;
  for (int idx = i; idx < DMODEL * KBIG; idx += stride) {
    int n = idx / KBIG, k = idx % KBIG;
    float v = (k < DSTATE) ? C[k * DMODEL + n] : D[(size_t)(k - DSTATE) * DMODEL + n];
    Wt[idx] = f2b(v);
  }
  for (int idx = i; idx < DSTATE * DMODEL; idx += stride) {
    int s = idx >> 10, k = idx & 1023;
    Btu[idx] = f2b(B[k * DSTATE + s]);
  }
  if (i < DSTATE) aSig[i] = 1.0f / (1.0f + expf(-A_diag[i]));
}

// cast x -> bf16 into Z[:, 64:1088]  (Z is [MTOT][KBIG] bf16)
__global__ void prep_x(const float* __restrict__ x, ushort* __restrict__ Z) {
  int i = blockIdx.x * blockDim.x + threadIdx.x;
  int stride = gridDim.x * blockDim.x;
  int total = MTOT * DMODEL / 4;
  for (int idx = i; idx < total; idx += stride) {
    float4 v = reinterpret_cast<const float4*>(x)[idx];
    int e = idx * 4;
    int m = e >> 10, k = e & 1023;
    ushort4 o;
    o.x = f2b(v.x); o.y = f2b(v.y); o.z = f2b(v.z); o.w = f2b(v.w);
    *reinterpret_cast<ushort4*>(&Z[(size_t)m * KBIG + DSTATE + k]) = o;
  }
}

// TN GEMM: C[m][n] = sum_k A[m][k] * Bt[n][k]; A [M][lda], Bt [N][ldb] bf16, C f32.
// 256 threads = 4 waves in 2x2; wave tile = (WM*16) x (WN*16). BK=64 fixed.
template<int BM, int BN, int WM, int WN>
__global__ __launch_bounds__(256) void gemm_tn(const ushort* __restrict__ A, int lda,
                                               const ushort* __restrict__ Bt, int ldb,
                                               float* __restrict__ Cc, int ldc, int K) {
  constexpr int BK = 64;
  constexpr int PAD = 8;
  __shared__ ushort As[BM][BK + PAD];
  __shared__ ushort Bs[BN][BK + PAD];
  int tid = threadIdx.x;
  int wid = tid >> 6, lane = tid & 63;
  int wm = wid >> 1, wn = wid & 1;
  int l16 = lane & 15, lh = lane >> 4;
  int row0 = blockIdx.x * BM;
  int col0 = blockIdx.y * BN;

  f32x4 acc[WM][WN] = {};

  for (int k0 = 0; k0 < K; k0 += BK) {
#pragma unroll
    for (int p = 0; p < BM * BK / (256 * 8); ++p) {
      int idx = tid + p * 256;
      int r = idx >> 3, c8 = (idx & 7) * 8;
      uint4 v = *reinterpret_cast<const uint4*>(&A[(size_t)(row0 + r) * lda + k0 + c8]);
      *reinterpret_cast<uint4*>(&As[r][c8]) = v;
    }
#pragma unroll
    for (int p = 0; p < BN * BK / (256 * 8); ++p) {
      int idx = tid + p * 256;
      int r = idx >> 3, c8 = (idx & 7) * 8;
      uint4 v = *reinterpret_cast<const uint4*>(&Bt[(size_t)(col0 + r) * ldb + k0 + c8]);
      *reinterpret_cast<uint4*>(&Bs[r][c8]) = v;
    }
    __syncthreads();
#pragma unroll
    for (int ks = 0; ks < 2; ++ks) {
      bf16x8 af[WM], bfr[WN];
#pragma unroll
      for (int m = 0; m < WM; ++m)
        af[m] = *reinterpret_cast<const bf16x8*>(&As[wm * WM * 16 + m * 16 + l16][ks * 32 + lh * 8]);
#pragma unroll
      for (int n = 0; n < WN; ++n)
        bfr[n] = *reinterpret_cast<const bf16x8*>(&Bs[wn * WN * 16 + n * 16 + l16][ks * 32 + lh * 8]);
#pragma unroll
      for (int m = 0; m < WM; ++m)
#pragma unroll
        for (int n = 0; n < WN; ++n)
          acc[m][n] = __builtin_amdgcn_mfma_f32_16x16x32_bf16(af[m], bfr[n], acc[m][n], 0, 0, 0);
    }
    __syncthreads();
  }

#pragma unroll
  for (int m = 0; m < WM; ++m)
#pragma unroll
    for (int n = 0; n < WN; ++n)
#pragma unroll
      for (int j = 0; j < 4; ++j) {
        int r = row0 + wm * WM * 16 + m * 16 + lh * 4 + j;
        int cc = col0 + wn * WN * 16 + n * 16 + l16;
        Cc[(size_t)r * ldc + cc] = acc[m][n][j];
      }
}

// chunk-local IIR scan, in-place on U (f32 [MTOT][64]); carry = final state per chunk
__global__ void scan_local(const float* __restrict__ aSig, float* __restrict__ U,
                           float* __restrict__ carry) {
  int b = blockIdx.x / NCH, c = blockIdx.x % NCH;
  int s = threadIdx.x;
  float as = aSig[s];
  float h = 0.0f;
  size_t base = ((size_t)b * 4096 + (size_t)c * TC) * DSTATE + s;
  for (int t = 0; t < TC; ++t) {
    float uu = U[base + (size_t)t * DSTATE];
    h = fmaf(as, h, uu);
    U[base + (size_t)t * DSTATE] = h;
  }
  carry[blockIdx.x * DSTATE + s] = h;
}

// combine carries exactly, write final h (bf16) into Z[:, 0:64]
__global__ void scan_fix(const float* __restrict__ aSig, const float* __restrict__ U,
                         const float* __restrict__ carry, ushort* __restrict__ Z) {
  int b = blockIdx.x / NCH, c = blockIdx.x % NCH;
  int s = threadIdx.x;
  float as = aSig[s];
  float aL = as;
#pragma unroll
  for (int q = 0; q < 9; ++q) aL *= aL;  // as^512 (underflows to 0 harmlessly)
  float H = 0.0f;
  for (int j = 0; j < c; ++j) H = fmaf(aL, H, carry[(b * NCH + j) * DSTATE + s]);
  size_t base = ((size_t)b * 4096 + (size_t)c * TC) * DSTATE + s;
  size_t zbase = ((size_t)b * 4096 + (size_t)c * TC) * KBIG + s;
  float p = as;
  for (int t = 0; t < TC; ++t) {
    float h = fmaf(p, H, U[base + (size_t)t * DSTATE]);
    p *= as;
    Z[zbase + (size_t)t * KBIG] = f2b(h);
  }
}

extern "C" void kernel_launch(void* const* d_in, const int* in_sizes, int n_in,
                              void* d_out, int out_size, void* d_ws, size_t ws_size,
                              hipStream_t stream) {
  const float* x      = (const float*)d_in[0];
  const float* A_diag = (const float*)d_in[1];
  const float* B      = (const float*)d_in[2];
  const float* C      = (const float*)d_in[3];
  const float* D      = (const float*)d_in[4];
  float* y = (float*)d_out;

  char* w = (char*)d_ws;
  ushort* Z     = (ushort*)(w);                 // [16384][1088] bf16  (35,651,584 B)
  ushort* Wt    = (ushort*)(w + 35651584);      // [1024][1088] bf16   (2,228,224 B)
  ushort* Btu   = (ushort*)(w + 37879808);      // [64][1024] bf16     (131,072 B)
  float*  U     = (float*) (w + 38010880);      // [16384][64] f32     (4,194,304 B)
  float*  carry = (float*) (w + 42205184);      // [4][8][64] f32      (8,192 B)
  float*  aSig  = (float*) (w + 42213376);      // [64] f32

  prep_params<<<dim3(1024), dim3(256), 0, stream>>>(A_diag, B, C, D, Wt, Btu, aSig);
  prep_x<<<dim3(2048), dim3(256), 0, stream>>>(x, Z);
  // u = x @ B : M=16384, N=64, K=1024
  gemm_tn<128, 64, 4, 2><<<dim3(128, 1), dim3(256), 0, stream>>>(Z + DSTATE, KBIG, Btu, DMODEL, U, DSTATE, DMODEL);
  scan_local<<<dim3(4 * NCH), dim3(64), 0, stream>>>(aSig, U, carry);
  scan_fix<<<dim3(4 * NCH), dim3(64), 0, stream>>>(aSig, U, carry, Z);
  // y = [h|x] @ [C;D] : M=16384, N=1024, K=1088
  gemm_tn<128, 128, 4, 4><<<dim3(128, 8), dim3(256), 0, stream>>>(Z, KBIG, Wt, KBIG, y, DMODEL, KBIG);
}

// Round 2
// 123.789 us; speedup vs baseline: 1.0809x; 1.0809x over previous
//
#include <hip/hip_runtime.h>
#include <hip/hip_bf16.h>

using bf16x8 = __attribute__((ext_vector_type(8))) __bf16;
using f32x4  = __attribute__((ext_vector_type(4))) float;

#define MTOT   16384
#define DMODEL 1024
#define DSTATE 64
#define KBIG   1088
#define NCH    64
#define TC     64

__device__ __forceinline__ ushort f2b(float f) {
  __hip_bfloat16 h = __float2bfloat16(f);
  return *reinterpret_cast<ushort*>(&h);
}

// async global->LDS, 16 bytes per lane. LDS dest = wave-uniform base + lane*16.
__device__ __forceinline__ void gld_lds16(const ushort* g, ushort* l) {
  using gptr_t = const __attribute__((address_space(1))) uint32_t*;
  using lptr_t = __attribute__((address_space(3))) uint32_t*;
  __builtin_amdgcn_global_load_lds(
      reinterpret_cast<gptr_t>(reinterpret_cast<uintptr_t>(g)),
      reinterpret_cast<lptr_t>(static_cast<uint32_t>(reinterpret_cast<uintptr_t>(l))),
      16, 0, 0);
}

// Build Wt[n][k] = bf16( k<64 ? C[k][n] : D[k-64][n] ), Btu[s][k] = bf16(B[k][s]),
// aSig[s] = sigmoid(A_diag[s])
__global__ void prep_params(const float* __restrict__ A_diag, const float* __restrict__ B,
                            const float* __restrict__ C, const float* __restrict__ D,
                            ushort* __restrict__ Wt, ushort* __restrict__ Btu,
                            float* __restrict__ aSig) {
  int i = blockIdx.x * blockDim.x + threadIdx.x;
  int stride = gridDim.x * blockDim.x;
  for (int idx = i; idx < DMODEL * KBIG; idx += stride) {
    int n = idx / KBIG, k = idx % KBIG;
    float v = (k < DSTATE) ? C[k * DMODEL + n] : D[(size_t)(k - DSTATE) * DMODEL + n];
    Wt[idx] = f2b(v);
  }
  for (int idx = i; idx < DSTATE * DMODEL; idx += stride) {
    int s = idx >> 10, k = idx & 1023;
    Btu[idx] = f2b(B[k * DSTATE + s]);
  }
  if (i < DSTATE) aSig[i] = 1.0f / (1.0f + expf(-A_diag[i]));
}

// cast x -> bf16 into Z[:, 64:1088]  (Z is [MTOT][KBIG] bf16); 8 elems/thread
__global__ void prep_x(const float* __restrict__ x, ushort* __restrict__ Z) {
  int i = blockIdx.x * blockDim.x + threadIdx.x;
  int stride = gridDim.x * blockDim.x;
  int total = MTOT * DMODEL / 8;
  for (int idx = i; idx < total; idx += stride) {
    float4 v0 = reinterpret_cast<const float4*>(x)[idx * 2];
    float4 v1 = reinterpret_cast<const float4*>(x)[idx * 2 + 1];
    int e = idx * 8;
    int m = e >> 10, k = e & 1023;
    ushort o[8] = {f2b(v0.x), f2b(v0.y), f2b(v0.z), f2b(v0.w),
                   f2b(v1.x), f2b(v1.y), f2b(v1.z), f2b(v1.w)};
    *reinterpret_cast<uint4*>(&Z[(size_t)m * KBIG + DSTATE + k]) =
        *reinterpret_cast<uint4*>(o);
  }
}

// TN GEMM (m97 structure): C[m][n] = sum_k A[m][k]*Bt[n][k].
// A [M][lda], Bt [N][ldb] bf16 (ushort), C f32. 256 thr = 4 waves (2x2),
// wave tile (WM*16)x(WN*16). BK=64. Staging via global_load_lds width=16,
// linear LDS [BM][64] (1KB call = 8 rows).
template<int BM, int BN, int WM, int WN>
__global__ __launch_bounds__(256) void gemm_tn(const ushort* __restrict__ A, int lda,
                                               const ushort* __restrict__ Bt, int ldb,
                                               float* __restrict__ Cc, int ldc, int K) {
  constexpr int BK = 64;
  __shared__ ushort As[BM][BK];
  __shared__ ushort Bs[BN][BK];
  int tid = threadIdx.x;
  int wid = tid >> 6, lane = tid & 63;
  int wm = wid >> 1, wn = wid & 1;
  int l16 = lane & 15, lh = lane >> 4;
  int row0 = blockIdx.x * BM;
  int col0 = blockIdx.y * BN;
  int lr = lane >> 3;        // row within 8-row call
  int lc = (lane & 7) * 8;   // col (ushorts)

  constexpr int CA = BM / 8;  // 1KB calls to fill As
  constexpr int CB = BN / 8;

  f32x4 acc[WM][WN] = {};

  for (int k0 = 0; k0 < K; k0 += BK) {
#pragma unroll
    for (int i = 0; i < CA / 4; ++i) {
      int q = wid * (CA / 4) + i;
      gld_lds16(&A[(size_t)(row0 + q * 8 + lr) * lda + k0 + lc], &As[0][0] + q * 512);
    }
#pragma unroll
    for (int i = 0; i < CB / 4; ++i) {
      int q = wid * (CB / 4) + i;
      gld_lds16(&Bt[(size_t)(col0 + q * 8 + lr) * ldb + k0 + lc], &Bs[0][0] + q * 512);
    }
    __syncthreads();
#pragma unroll
    for (int ks = 0; ks < 2; ++ks) {
      bf16x8 af[WM], bfr[WN];
#pragma unroll
      for (int m = 0; m < WM; ++m)
        af[m] = *reinterpret_cast<const bf16x8*>(&As[wm * WM * 16 + m * 16 + l16][ks * 32 + lh * 8]);
#pragma unroll
      for (int n = 0; n < WN; ++n)
        bfr[n] = *reinterpret_cast<const bf16x8*>(&Bs[wn * WN * 16 + n * 16 + l16][ks * 32 + lh * 8]);
#pragma unroll
      for (int m = 0; m < WM; ++m)
#pragma unroll
        for (int n = 0; n < WN; ++n)
          acc[m][n] = __builtin_amdgcn_mfma_f32_16x16x32_bf16(af[m], bfr[n], acc[m][n], 0, 0, 0);
    }
    __syncthreads();
  }

#pragma unroll
  for (int m = 0; m < WM; ++m)
#pragma unroll
    for (int n = 0; n < WN; ++n)
#pragma unroll
      for (int j = 0; j < 4; ++j) {
        int r = row0 + wm * WM * 16 + m * 16 + lh * 4 + j;
        int cc = col0 + wn * WN * 16 + n * 16 + l16;
        Cc[(size_t)r * ldc + cc] = acc[m][n][j];
      }
}

// pass 1: chunk-final state only (read-only over U). 1 wave = 1 chunk of 64 steps.
__global__ void scan_carry(const float* __restrict__ aSig, const float* __restrict__ U,
                           float* __restrict__ carry) {
  int wid = threadIdx.x >> 6;
  int chunk = blockIdx.x * 4 + wid;            // 0..255
  int b = chunk >> 6, c = chunk & (NCH - 1);
  int s = threadIdx.x & 63;
  float as = aSig[s];
  size_t base = ((size_t)b * 4096 + (size_t)c * TC) * DSTATE + s;
  float h = 0.0f;
#pragma unroll
  for (int t = 0; t < TC; ++t) h = fmaf(as, h, U[base + (size_t)t * DSTATE]);
  carry[chunk * DSTATE + s] = h;
}

// pass 2: combine carries (H before chunk), recompute scan, write bf16 h into Z[:,0:64]
__global__ void scan_fix(const float* __restrict__ aSig, const float* __restrict__ U,
                         const float* __restrict__ carry, ushort* __restrict__ Z) {
  int wid = threadIdx.x >> 6;
  int chunk = blockIdx.x * 4 + wid;
  int b = chunk >> 6, c = chunk & (NCH - 1);
  int s = threadIdx.x & 63;
  float as = aSig[s];
  float aL = as;
#pragma unroll
  for (int q = 0; q < 6; ++q) aL *= aL;        // as^64
  float H = 0.0f;
  for (int j = 0; j < c; ++j) H = fmaf(aL, H, carry[(b * NCH + j) * DSTATE + s]);
  size_t base  = ((size_t)b * 4096 + (size_t)c * TC) * DSTATE + s;
  size_t zbase = ((size_t)b * 4096 + (size_t)c * TC) * KBIG + s;
  float h = H;
#pragma unroll 8
  for (int t = 0; t < TC; ++t) {
    h = fmaf(as, h, U[base + (size_t)t * DSTATE]);
    Z[zbase + (size_t)t * KBIG] = f2b(h);
  }
}

extern "C" void kernel_launch(void* const* d_in, const int* in_sizes, int n_in,
                              void* d_out, int out_size, void* d_ws, size_t ws_size,
                              hipStream_t stream) {
  const float* x      = (const float*)d_in[0];
  const float* A_diag = (const float*)d_in[1];
  const float* B      = (const float*)d_in[2];
  const float* C      = (const float*)d_in[3];
  const float* D      = (const float*)d_in[4];
  float* y = (float*)d_out;

  char* w = (char*)d_ws;
  ushort* Z     = (ushort*)(w);                 // [16384][1088] bf16  (35,651,584 B)
  ushort* Wt    = (ushort*)(w + 35651584);      // [1024][1088] bf16   (2,228,224 B)
  ushort* Btu   = (ushort*)(w + 37879808);      // [64][1024] bf16     (131,072 B)
  float*  U     = (float*) (w + 38010880);      // [16384][64] f32     (4,194,304 B)
  float*  carry = (float*) (w + 42205184);      // [256][64] f32       (65,536 B)
  float*  aSig  = (float*) (w + 42270720);      // [64] f32

  prep_params<<<dim3(1024), dim3(256), 0, stream>>>(A_diag, B, C, D, Wt, Btu, aSig);
  prep_x<<<dim3(2048), dim3(256), 0, stream>>>(x, Z);
  // u = x @ B : M=16384, N=64, K=1024  (64x64 tile -> 256 blocks)
  gemm_tn<64, 64, 2, 2><<<dim3(256, 1), dim3(256), 0, stream>>>(Z + DSTATE, KBIG, Btu, DMODEL, U, DSTATE, DMODEL);
  scan_carry<<<dim3(4 * NCH / 4), dim3(256), 0, stream>>>(aSig, U, carry);
  scan_fix<<<dim3(4 * NCH / 4), dim3(256), 0, stream>>>(aSig, U, carry, Z);
  // y = [h|x] @ [C;D] : M=16384, N=1024, K=1088
  gemm_tn<128, 128, 4, 4><<<dim3(128, 8), dim3(256), 0, stream>>>(Z, KBIG, Wt, KBIG, y, DMODEL, KBIG);
}

// Round 3
// 107.944 us; speedup vs baseline: 1.2395x; 1.1468x over previous
//
#include <hip/hip_runtime.h>
#include <hip/hip_bf16.h>

using bf16x8 = __attribute__((ext_vector_type(8))) __bf16;
using f32x4  = __attribute__((ext_vector_type(4))) float;

#define MTOT   16384
#define DMODEL 1024
#define DSTATE 64
#define KBIG   1088
#define NCH    64
#define TC     64

__device__ __forceinline__ ushort f2b(float f) {
  __hip_bfloat16 h = __float2bfloat16(f);
  return *reinterpret_cast<ushort*>(&h);
}

// async global->LDS, 16 bytes per lane. LDS dest = wave-uniform base + lane*16.
__device__ __forceinline__ void gld_lds16(const ushort* g, const char* l) {
  using gptr_t = const __attribute__((address_space(1))) uint32_t*;
  using lptr_t = __attribute__((address_space(3))) uint32_t*;
  __builtin_amdgcn_global_load_lds(
      reinterpret_cast<gptr_t>(reinterpret_cast<uintptr_t>(g)),
      reinterpret_cast<lptr_t>(static_cast<uint32_t>(reinterpret_cast<uintptr_t>(l))),
      16, 0, 0);
}

#define BARRIER() do { asm volatile("" ::: "memory"); __builtin_amdgcn_s_barrier(); asm volatile("" ::: "memory"); } while (0)
#define VMCNT4() asm volatile("s_waitcnt vmcnt(4)" ::: "memory")
#define VMCNT0() asm volatile("s_waitcnt vmcnt(0)" ::: "memory")

// ---------------- prep kernels ----------------

__global__ void prep_params(const float* __restrict__ A_diag, const float* __restrict__ B,
                            const float* __restrict__ C, const float* __restrict__ D,
                            ushort* __restrict__ Wt, ushort* __restrict__ Btu,
                            float* __restrict__ aSig) {
  int i = blockIdx.x * blockDim.x + threadIdx.x;
  int stride = gridDim.x * blockDim.x;
  for (int idx = i; idx < DMODEL * KBIG; idx += stride) {
    int n = idx / KBIG, k = idx % KBIG;
    float v = (k < DSTATE) ? C[k * DMODEL + n] : D[(size_t)(k - DSTATE) * DMODEL + n];
    Wt[idx] = f2b(v);
  }
  for (int idx = i; idx < DSTATE * DMODEL; idx += stride) {
    int s = idx >> 10, k = idx & 1023;
    Btu[idx] = f2b(B[k * DSTATE + s]);
  }
  if (i < DSTATE) aSig[i] = 1.0f / (1.0f + expf(-A_diag[i]));
}

__global__ void prep_x(const float* __restrict__ x, ushort* __restrict__ Z) {
  int i = blockIdx.x * blockDim.x + threadIdx.x;
  int stride = gridDim.x * blockDim.x;
  int total = MTOT * DMODEL / 8;
  for (int idx = i; idx < total; idx += stride) {
    float4 v0 = reinterpret_cast<const float4*>(x)[idx * 2];
    float4 v1 = reinterpret_cast<const float4*>(x)[idx * 2 + 1];
    int e = idx * 8;
    int m = e >> 10, k = e & 1023;
    ushort o[8] = {f2b(v0.x), f2b(v0.y), f2b(v0.z), f2b(v0.w),
                   f2b(v1.x), f2b(v1.y), f2b(v1.z), f2b(v1.w)};
    *reinterpret_cast<uint4*>(&Z[(size_t)m * KBIG + DSTATE + k]) =
        *reinterpret_cast<uint4*>(o);
  }
}

// ---------------- small TN GEMM (m97-ish, for u = x@B) ----------------

template<int BM, int BN, int WM, int WN>
__global__ __launch_bounds__(256) void gemm_tn(const ushort* __restrict__ A, int lda,
                                               const ushort* __restrict__ Bt, int ldb,
                                               float* __restrict__ Cc, int ldc, int K) {
  constexpr int BK = 64;
  __shared__ ushort As[BM][BK];
  __shared__ ushort Bs[BN][BK];
  int tid = threadIdx.x;
  int wid = tid >> 6, lane = tid & 63;
  int wm = wid >> 1, wn = wid & 1;
  int l16 = lane & 15, lh = lane >> 4;
  int row0 = blockIdx.x * BM;
  int col0 = blockIdx.y * BN;
  int lr = lane >> 3;
  int lc = (lane & 7) * 8;

  constexpr int CA = BM / 8;
  constexpr int CB = BN / 8;

  f32x4 acc[WM][WN] = {};

  for (int k0 = 0; k0 < K; k0 += BK) {
#pragma unroll
    for (int i = 0; i < CA / 4; ++i) {
      int q = wid * (CA / 4) + i;
      gld_lds16(&A[(size_t)(row0 + q * 8 + lr) * lda + k0 + lc], (const char*)(&As[0][0] + q * 512));
    }
#pragma unroll
    for (int i = 0; i < CB / 4; ++i) {
      int q = wid * (CB / 4) + i;
      gld_lds16(&Bt[(size_t)(col0 + q * 8 + lr) * ldb + k0 + lc], (const char*)(&Bs[0][0] + q * 512));
    }
    __syncthreads();
#pragma unroll
    for (int ks = 0; ks < 2; ++ks) {
      bf16x8 af[WM], bfr[WN];
#pragma unroll
      for (int m = 0; m < WM; ++m)
        af[m] = *reinterpret_cast<const bf16x8*>(&As[wm * WM * 16 + m * 16 + l16][ks * 32 + lh * 8]);
#pragma unroll
      for (int n = 0; n < WN; ++n)
        bfr[n] = *reinterpret_cast<const bf16x8*>(&Bs[wn * WN * 16 + n * 16 + l16][ks * 32 + lh * 8]);
#pragma unroll
      for (int m = 0; m < WM; ++m)
#pragma unroll
        for (int n = 0; n < WN; ++n)
          acc[m][n] = __builtin_amdgcn_mfma_f32_16x16x32_bf16(af[m], bfr[n], acc[m][n], 0, 0, 0);
    }
    __syncthreads();
  }

#pragma unroll
  for (int m = 0; m < WM; ++m)
#pragma unroll
    for (int n = 0; n < WN; ++n)
#pragma unroll
      for (int j = 0; j < 4; ++j) {
        int r = row0 + wm * WM * 16 + m * 16 + lh * 4 + j;
        int cc = col0 + wn * WN * 16 + n * 16 + l16;
        Cc[(size_t)r * ldc + cc] = acc[m][n][j];
      }
}

// ---------------- 256x256 8-phase GEMM (big: y = Z @ Wt^T) ----------------
// A [M][lda], Bt [N][ldb] bf16 k-contiguous. M%256==0, N%256==0, K%64==0.
// 512 thr = 8 waves (2 x 4). LDS: 2 bufs x (A[256][64] + B[256][64]) = 128 KiB.
// st_16x32 swizzle: LDS col ^= 16 ushorts when (row & 4), applied on the
// global SOURCE address (linear gld_lds dest) and on the ds_read address.
__global__ __launch_bounds__(512) void gemm256(const ushort* __restrict__ A, int lda,
                                               const ushort* __restrict__ Bt, int ldb,
                                               float* __restrict__ Cc, int ldc, int K) {
  extern __shared__ __align__(128) char smem[];
  const int tid = threadIdx.x;
  const int wid = tid >> 6, lane = tid & 63;
  const int wm = wid >> 2, wn = wid & 3;      // 2 x 4 wave grid
  const int l16 = lane & 15, lh = lane >> 4;  // frag lane decomposition

  int bid = blockIdx.x;
  int swz = (bid & 7) * ((int)gridDim.x >> 3) + (bid >> 3);  // XCD swizzle (nwg%8==0)
  const int bmRow = (swz >> 2) * 256;   // N/256 = 4 block-cols
  const int bnCol = (swz & 3) * 256;

  const int NT = K / 64;

  // per-thread read bases (byte offsets within a buffer)
  const int rswz = (l16 & 4) ? 32 : 0;  // swizzle: flip 16-ushort group (32 B)
  const int aRB = (wm * 128 + l16) * 128 + ((lh * 16) ^ rswz);
  const int bRB = 32768 + (wn * 64 + l16) * 128 + ((lh * 16) ^ rswz);

  // per-lane stage source column swizzle (LDS row bit2 == lane bit5)
  const int sRow = lane >> 3;
  const int sCol = ((lane & 7) * 8) ^ ((lane & 32) ? 16 : 0);

  f32x4 acc[8][4] = {};
  bf16x8 aR[8], bR[8];

  auto stageA = [&](int buf, int t, int h) {
    size_t r = (size_t)(bmRow + h * 128 + wid * 8 + sRow);
    const ushort* g0 = A + r * (size_t)lda + t * 64 + sCol;
    const char* d = smem + buf * 65536 + (h * 128 + wid * 8) * 128;
    gld_lds16(g0, d);
    gld_lds16(g0 + (size_t)64 * lda, d + 64 * 128);
  };
  auto stageB = [&](int buf, int t, int h) {
    size_t r = (size_t)(bnCol + h * 128 + wid * 8 + sRow);
    const ushort* g0 = Bt + r * (size_t)ldb + t * 64 + sCol;
    const char* d = smem + buf * 65536 + 32768 + (h * 128 + wid * 8) * 128;
    gld_lds16(g0, d);
    gld_lds16(g0 + (size_t)64 * ldb, d + 64 * 128);
  };
  auto loadA = [&](int buf, int qm) {
#pragma unroll
    for (int m = 0; m < 4; ++m)
#pragma unroll
      for (int ks = 0; ks < 2; ++ks)
        aR[m * 2 + ks] = *reinterpret_cast<const bf16x8*>(
            smem + buf * 65536 + aRB + (qm * 64 + m * 16) * 128 + ks * 64);
  };
  auto loadB = [&](int buf, int qn) {
#pragma unroll
    for (int n = 0; n < 2; ++n)
#pragma unroll
      for (int ks = 0; ks < 2; ++ks)
        bR[qn * 4 + n * 2 + ks] = *reinterpret_cast<const bf16x8*>(
            smem + buf * 65536 + bRB + (qn * 32 + n * 16) * 128 + ks * 64);
  };
  auto mfmaQ = [&](int qm, int qn) {
    __builtin_amdgcn_s_setprio(1);
    __builtin_amdgcn_sched_barrier(0);
#pragma unroll
    for (int m = 0; m < 4; ++m)
#pragma unroll
      for (int n = 0; n < 2; ++n)
#pragma unroll
        for (int ks = 0; ks < 2; ++ks)
          acc[qm * 4 + m][qn * 2 + n] = __builtin_amdgcn_mfma_f32_16x16x32_bf16(
              aR[m * 2 + ks], bR[qn * 4 + n * 2 + ks], acc[qm * 4 + m][qn * 2 + n], 0, 0, 0);
    __builtin_amdgcn_sched_barrier(0);
    __builtin_amdgcn_s_setprio(0);
  };

  // prologue: stage tiles 0 (buf0) and 1 (buf1) fully, drain, barrier
  stageA(0, 0, 0); stageA(0, 0, 1); stageB(0, 0, 0); stageB(0, 0, 1);
  if (1 < NT) { stageA(1, 1, 0); stageA(1, 1, 1); stageB(1, 1, 0); stageB(1, 1, 1); }
  VMCNT0();
  BARRIER();

  for (int t = 0; t < NT; t += 2) {
    const bool s01 = (t > 0) && (t + 1 < NT);
    const bool s23 = (t + 2 < NT);
    const bool s67 = (t + 3 < NT);
    // ---- tile t @ buf0 ----
    loadA(0, 0); loadB(0, 0);
    if (s01) stageA(1, t + 1, 0);
    BARRIER(); mfmaQ(0, 0); BARRIER();
    loadB(0, 1);
    if (s01) stageA(1, t + 1, 1);
    BARRIER(); mfmaQ(0, 1); BARRIER();
    loadA(0, 1);
    if (s23) stageB(0, t + 2, 0);
    BARRIER(); mfmaQ(1, 0); BARRIER();
    if (s23) stageB(0, t + 2, 1);
    BARRIER(); mfmaQ(1, 1);
    if (s23) { VMCNT4(); } else { VMCNT0(); }
    BARRIER();
    // ---- tile t+1 @ buf1 ----
    if (t + 1 < NT) {
      loadA(1, 0); loadB(1, 0);
      if (s23) stageA(0, t + 2, 0);
      BARRIER(); mfmaQ(0, 0); BARRIER();
      loadB(1, 1);
      if (s23) stageA(0, t + 2, 1);
      BARRIER(); mfmaQ(0, 1); BARRIER();
      loadA(1, 1);
      if (s67) stageB(1, t + 3, 0);
      BARRIER(); mfmaQ(1, 0); BARRIER();
      if (s67) stageB(1, t + 3, 1);
      BARRIER(); mfmaQ(1, 1);
      if (s67) { VMCNT4(); } else { VMCNT0(); }
      BARRIER();
    }
  }

  // epilogue
#pragma unroll
  for (int i = 0; i < 8; ++i)
#pragma unroll
    for (int jn = 0; jn < 4; ++jn)
#pragma unroll
      for (int j = 0; j < 4; ++j) {
        int r = bmRow + wm * 128 + (i >> 2) * 64 + (i & 3) * 16 + lh * 4 + j;
        int c = bnCol + wn * 64 + (jn >> 1) * 32 + (jn & 1) * 16 + l16;
        Cc[(size_t)r * ldc + c] = acc[i][jn][j];
      }
}

// ---------------- scan kernels ----------------

__global__ void scan_carry(const float* __restrict__ aSig, const float* __restrict__ U,
                           float* __restrict__ carry) {
  int wid = threadIdx.x >> 6;
  int chunk = blockIdx.x * 4 + wid;
  int b = chunk >> 6, c = chunk & (NCH - 1);
  int s = threadIdx.x & 63;
  float as = aSig[s];
  size_t base = ((size_t)b * 4096 + (size_t)c * TC) * DSTATE + s;
  float h = 0.0f;
#pragma unroll
  for (int t = 0; t < TC; ++t) h = fmaf(as, h, U[base + (size_t)t * DSTATE]);
  carry[chunk * DSTATE + s] = h;
}

__global__ void scan_fix(const float* __restrict__ aSig, const float* __restrict__ U,
                         const float* __restrict__ carry, ushort* __restrict__ Z) {
  int wid = threadIdx.x >> 6;
  int chunk = blockIdx.x * 4 + wid;
  int b = chunk >> 6, c = chunk & (NCH - 1);
  int s = threadIdx.x & 63;
  float as = aSig[s];
  float aL = as;
#pragma unroll
  for (int q = 0; q < 6; ++q) aL *= aL;  // as^64
  float H = 0.0f;
  for (int j = 0; j < c; ++j) H = fmaf(aL, H, carry[(b * NCH + j) * DSTATE + s]);
  size_t base  = ((size_t)b * 4096 + (size_t)c * TC) * DSTATE + s;
  size_t zbase = ((size_t)b * 4096 + (size_t)c * TC) * KBIG + s;
  float h = H;
#pragma unroll 8
  for (int t = 0; t < TC; ++t) {
    h = fmaf(as, h, U[base + (size_t)t * DSTATE]);
    Z[zbase + (size_t)t * KBIG] = f2b(h);
  }
}

extern "C" void kernel_launch(void* const* d_in, const int* in_sizes, int n_in,
                              void* d_out, int out_size, void* d_ws, size_t ws_size,
                              hipStream_t stream) {
  const float* x      = (const float*)d_in[0];
  const float* A_diag = (const float*)d_in[1];
  const float* B      = (const float*)d_in[2];
  const float* C      = (const float*)d_in[3];
  const float* D      = (const float*)d_in[4];
  float* y = (float*)d_out;

  char* w = (char*)d_ws;
  ushort* Z     = (ushort*)(w);                 // [16384][1088] bf16
  ushort* Wt    = (ushort*)(w + 35651584);      // [1024][1088] bf16
  ushort* Btu   = (ushort*)(w + 37879808);      // [64][1024] bf16
  float*  U     = (float*) (w + 38010880);      // [16384][64] f32
  float*  carry = (float*) (w + 42205184);      // [256][64] f32
  float*  aSig  = (float*) (w + 42270720);      // [64] f32

  static bool attr_set = false;
  if (!attr_set) {
    (void)hipFuncSetAttribute(reinterpret_cast<const void*>(&gemm256),
                              hipFuncAttributeMaxDynamicSharedMemorySize, 131072);
    attr_set = true;
  }

  prep_params<<<dim3(1024), dim3(256), 0, stream>>>(A_diag, B, C, D, Wt, Btu, aSig);
  prep_x<<<dim3(2048), dim3(256), 0, stream>>>(x, Z);
  // u = x @ B : M=16384, N=64, K=1024
  gemm_tn<64, 64, 2, 2><<<dim3(256, 1), dim3(256), 0, stream>>>(Z + DSTATE, KBIG, Btu, DMODEL, U, DSTATE, DMODEL);
  scan_carry<<<dim3(4 * NCH / 4), dim3(256), 0, stream>>>(aSig, U, carry);
  scan_fix<<<dim3(4 * NCH / 4), dim3(256), 0, stream>>>(aSig, U, carry, Z);
  // y = [h|x] @ [C;D] : M=16384, N=1024, K=1088  (256x256 tiles -> 256 blocks)
  gemm256<<<dim3(64 * 4), dim3(512), 131072, stream>>>(Z, KBIG, Wt, KBIG, y, DMODEL, KBIG);
}